// Round 1
// baseline (1113.240 us; speedup 1.0000x reference)
//
#include <hip/hip_runtime.h>
#include <hip/hip_bf16.h>

#define BB 4
#define MM 50000
#define FINF 128
#define FOUTF 128
#define KCH 4
#define EE 800000
#define NROWS (BB*MM)      // 200000
#define XC 512             // columns of X = B*FIN
#define CD 512             // reduction dim = FIN*K

__device__ __forceinline__ float bf2f(unsigned short u){
    union{unsigned int i; float f;} v; v.i = ((unsigned int)u) << 16; return v.f;
}
__device__ __forceinline__ unsigned short f2bf(float f){
    union{float f; unsigned int i;} v; v.f = f;
    unsigned int r = v.i + 0x7FFF + ((v.i >> 16) & 1);   // RNE
    return (unsigned short)(r >> 16);
}

typedef __bf16 bf16x8 __attribute__((ext_vector_type(8)));
typedef float  f32x4  __attribute__((ext_vector_type(4)));

// ---- X0[m][b*128+f] = bf16(x[b][m][f]) ----
__global__ __launch_bounds__(256) void k_init_x0(const float* __restrict__ x,
                                                 unsigned short* __restrict__ X0){
    int tid = blockIdx.x*256 + threadIdx.x;          // one float4 each
    if (tid >= BB*MM*FINF/4) return;
    int f4 = tid & 31;
    int t  = tid >> 5;                               // b*MM + m
    int m  = t % MM, b = t / MM;
    float4 v = ((const float4*)x)[tid];
    ushort4 o;
    o.x = f2bf(v.x); o.y = f2bf(v.y); o.z = f2bf(v.z); o.w = f2bf(v.w);
    *(ushort4*)(X0 + (size_t)m*XC + b*FINF + f4*4) = o;
}

// ---- Wt[n][k*128+f] = bf16(kernel[(f*K+k)*128 + n]) ----
__global__ __launch_bounds__(256) void k_prepw(const float* __restrict__ kern,
                                               unsigned short* __restrict__ Wt){
    int tid = blockIdx.x*256 + threadIdx.x;          // 65536
    int c = tid & 511, n = tid >> 9;
    int kc = c >> 7, f = c & 127;
    Wt[n*CD + c] = f2bf(kern[(f*KCH + kc)*FOUTF + n]);
}

// ---- CSR build ----
__global__ __launch_bounds__(256) void k_hist(const int* __restrict__ rows, int* __restrict__ counts){
    int e = blockIdx.x*256 + threadIdx.x;
    if (e < EE) atomicAdd(&counts[rows[e]], 1);
}

__global__ __launch_bounds__(1024) void k_scan(const int* __restrict__ counts,
                                               int* __restrict__ offs, int* __restrict__ cursor){
    __shared__ int part[1024];
    const int CH = (MM + 1023) / 1024;               // 49
    int t = threadIdx.x;
    int lo = t*CH; if (lo > MM) lo = MM;
    int hi = lo + CH; if (hi > MM) hi = MM;
    int s = 0;
    for (int i = lo; i < hi; ++i) s += counts[i];
    part[t] = s; __syncthreads();
    for (int d = 1; d < 1024; d <<= 1){
        int v = (t >= d) ? part[t-d] : 0;
        __syncthreads();
        part[t] += v;
        __syncthreads();
    }
    int run = (t == 0) ? 0 : part[t-1];
    for (int i = lo; i < hi; ++i){
        offs[i] = run; cursor[i] = run; run += counts[i];
    }
    if (t == 1023) offs[MM] = part[1023];
}

__global__ __launch_bounds__(256) void k_scatter(const int* __restrict__ rows, const int* __restrict__ cols,
                                                 const float* __restrict__ vals, int* __restrict__ cursor,
                                                 int* __restrict__ colv, float* __restrict__ valv){
    int e = blockIdx.x*256 + threadIdx.x;
    if (e >= EE) return;
    int r = rows[e];
    int pos = atomicAdd(&cursor[r], 1);
    colv[pos] = cols[e]; valv[pos] = vals[e];
}

// ---- Xout = alpha * (L @ Xin) - (sub ? Xprev : 0), one block per row ----
__global__ __launch_bounds__(128) void k_spmm(const unsigned short* __restrict__ Xin,
                                              const unsigned short* __restrict__ Xprev,
                                              unsigned short* __restrict__ Xout,
                                              const int* __restrict__ offs,
                                              const int* __restrict__ colv,
                                              const float* __restrict__ valv,
                                              float alpha, int sub){
    int m = blockIdx.x, t = threadIdx.x;
    int c0 = t*4;
    int start = offs[m], end = offs[m+1];
    float a0=0.f, a1=0.f, a2=0.f, a3=0.f;
    for (int j = start; j < end; ++j){
        int col = colv[j]; float val = valv[j];
        ushort4 xv = *(const ushort4*)(Xin + (size_t)col*XC + c0);
        a0 += val*bf2f(xv.x); a1 += val*bf2f(xv.y);
        a2 += val*bf2f(xv.z); a3 += val*bf2f(xv.w);
    }
    a0 *= alpha; a1 *= alpha; a2 *= alpha; a3 *= alpha;
    if (sub){
        ushort4 pv = *(const ushort4*)(Xprev + (size_t)m*XC + c0);
        a0 -= bf2f(pv.x); a1 -= bf2f(pv.y); a2 -= bf2f(pv.z); a3 -= bf2f(pv.w);
    }
    ushort4 o; o.x = f2bf(a0); o.y = f2bf(a1); o.z = f2bf(a2); o.w = f2bf(a3);
    *(ushort4*)(Xout + (size_t)m*XC + c0) = o;
}

// ---- Y[r][n] = relu(sum_c A[r][c]*Wt[n][c]); A[r][k*128+f] = Xk[m][b*128+f], r=b*M+m ----
__global__ __launch_bounds__(256) void k_gemm(const unsigned short* __restrict__ X0,
                                              const unsigned short* __restrict__ X1,
                                              const unsigned short* __restrict__ X2,
                                              const unsigned short* __restrict__ X3,
                                              const unsigned short* __restrict__ Wt,
                                              float* __restrict__ Y){
    const int wave = threadIdx.x >> 6;
    const int lane = threadIdx.x & 63;
    const int l16  = lane & 15;
    const int g    = lane >> 4;                       // 0..3
    const int r0   = blockIdx.x*128 + wave*32;
    int ra0 = r0 + l16;      if (ra0 >= NROWS) ra0 = NROWS-1;
    int ra1 = r0 + 16 + l16; if (ra1 >= NROWS) ra1 = NROWS-1;
    const size_t aoff0 = (size_t)(ra0 % MM)*XC + (ra0 / MM)*FINF + g*8;
    const size_t aoff1 = (size_t)(ra1 % MM)*XC + (ra1 / MM)*FINF + g*8;
    const int wrow = l16*CD + g*8;                    // base into Wt

    f32x4 acc[2][8];
    #pragma unroll
    for (int i = 0; i < 2; ++i)
        #pragma unroll
        for (int j = 0; j < 8; ++j) acc[i][j] = (f32x4){0.f,0.f,0.f,0.f};

    const unsigned short* const Xs[4] = {X0, X1, X2, X3};
    #pragma unroll
    for (int kb = 0; kb < 4; ++kb){
        const unsigned short* Xb = Xs[kb];
        #pragma unroll
        for (int ki = 0; ki < 4; ++ki){
            const int f0 = ki*32;
            bf16x8 a0 = *(const bf16x8*)(Xb + aoff0 + f0);
            bf16x8 a1 = *(const bf16x8*)(Xb + aoff1 + f0);
            const int c0 = (kb*4 + ki)*32;            // reduction offset (g*8 already in wrow)
            #pragma unroll
            for (int ns = 0; ns < 8; ++ns){
                bf16x8 bb = *(const bf16x8*)(Wt + wrow + ns*16*CD + c0);
                acc[0][ns] = __builtin_amdgcn_mfma_f32_16x16x32_bf16(a0, bb, acc[0][ns], 0, 0, 0);
                acc[1][ns] = __builtin_amdgcn_mfma_f32_16x16x32_bf16(a1, bb, acc[1][ns], 0, 0, 0);
            }
        }
    }
    #pragma unroll
    for (int msub = 0; msub < 2; ++msub){
        #pragma unroll
        for (int reg = 0; reg < 4; ++reg){
            int r = r0 + msub*16 + g*4 + reg;
            if (r < NROWS){
                #pragma unroll
                for (int ns = 0; ns < 8; ++ns){
                    float v = acc[msub][ns][reg];
                    Y[(size_t)r*FOUTF + ns*16 + l16] = v > 0.f ? v : 0.f;
                }
            }
        }
    }
}

// ---- column sums of relu'd Y per batch ----
__global__ __launch_bounds__(128) void k_colmean(const float* __restrict__ Y, float* __restrict__ sacc){
    int b = blockIdx.y, t = threadIdx.x;
    int m0 = blockIdx.x*512;
    int mend = m0 + 512; if (mend > MM) mend = MM;
    float s = 0.f;
    for (int m = m0; m < mend; ++m) s += Y[((size_t)b*MM + m)*FOUTF + t];
    atomicAdd(&sacc[b*FOUTF + t], s);
}

// ---- SE MLP: u = sigmoid(swish(mean @ Wd + bd) @ Wu + bu) ----
__global__ __launch_bounds__(128) void k_se(const float* __restrict__ sacc,
                                            const float* __restrict__ Wd, const float* __restrict__ bd,
                                            const float* __restrict__ Wu, const float* __restrict__ bu,
                                            float* __restrict__ u){
    int b = blockIdx.x, t = threadIdx.x;
    __shared__ float sm[128];
    __shared__ float dsh[16];
    sm[t] = sacc[b*FOUTF + t] * (1.0f/MM);
    __syncthreads();
    if (t < 16){
        float a = bd[t];
        for (int f = 0; f < 128; ++f) a += sm[f]*Wd[f*16 + t];
        dsh[t] = a / (1.f + expf(-a));                // swish
    }
    __syncthreads();
    float a = bu[t];
    for (int j = 0; j < 16; ++j) a += dsh[j]*Wu[j*FOUTF + t];
    u[b*FOUTF + t] = 1.f/(1.f + expf(-a));
}

// ---- out = Y * u[b] ----
__global__ __launch_bounds__(256) void k_scale(const float* __restrict__ Y, const float* __restrict__ u,
                                               float* __restrict__ out){
    int tid = blockIdx.x*256 + threadIdx.x;
    if (tid >= NROWS*FOUTF/4) return;
    int b  = tid / (MM*FOUTF/4);
    int f4 = tid & 31;
    float4 yv = ((const float4*)Y)[tid];
    float4 uv = *(const float4*)(u + b*FOUTF + f4*4);
    float4 o;
    o.x = yv.x*uv.x; o.y = yv.y*uv.y; o.z = yv.z*uv.z; o.w = yv.w*uv.w;
    ((float4*)out)[tid] = o;
}

extern "C" void kernel_launch(void* const* d_in, const int* in_sizes, int n_in,
                              void* d_out, int out_size, void* d_ws, size_t ws_size,
                              hipStream_t stream){
    (void)in_sizes; (void)n_in; (void)out_size; (void)ws_size;
    const float* x    = (const float*)d_in[0];
    const float* lv   = (const float*)d_in[1];
    const int*   lr   = (const int*)d_in[2];
    const int*   lc   = (const int*)d_in[3];
    const float* kern = (const float*)d_in[4];
    const float* Wd   = (const float*)d_in[5];
    const float* bd   = (const float*)d_in[6];
    const float* Wu   = (const float*)d_in[7];
    const float* bu   = (const float*)d_in[8];
    float* out = (float*)d_out;

    char* w = (char*)d_ws;
    size_t off = 0;
    auto take = [&](size_t bytes)->char*{
        char* p = w + off; off += (bytes + 255) & ~(size_t)255; return p;
    };
    unsigned short* X[4];
    for (int i = 0; i < 4; ++i) X[i] = (unsigned short*)take((size_t)MM*XC*2);
    float* Y           = (float*)take((size_t)NROWS*FOUTF*4);
    unsigned short* Wt = (unsigned short*)take((size_t)FOUTF*CD*2);
    int* counts        = (int*)take((size_t)MM*4);
    int* offs          = (int*)take((size_t)(MM+1)*4);
    int* cursor        = (int*)take((size_t)MM*4);
    int* colv          = (int*)take((size_t)EE*4);
    float* valv        = (float*)take((size_t)EE*4);
    float* sacc        = (float*)take((size_t)BB*FOUTF*4);
    float* u           = (float*)take((size_t)BB*FOUTF*4);

    hipMemsetAsync(counts, 0, MM*4, stream);
    hipMemsetAsync(sacc, 0, BB*FOUTF*4, stream);

    k_init_x0<<<25000, 256, 0, stream>>>(x, X[0]);
    k_prepw<<<256, 256, 0, stream>>>(kern, Wt);
    k_hist<<<(EE+255)/256, 256, 0, stream>>>(lr, counts);
    k_scan<<<1, 1024, 0, stream>>>(counts, offs, cursor);
    k_scatter<<<(EE+255)/256, 256, 0, stream>>>(lr, lc, lv, cursor, colv, valv);

    k_spmm<<<MM, 128, 0, stream>>>(X[0], X[0], X[1], offs, colv, valv, 1.0f, 0);
    k_spmm<<<MM, 128, 0, stream>>>(X[1], X[0], X[2], offs, colv, valv, 2.0f, 1);
    k_spmm<<<MM, 128, 0, stream>>>(X[2], X[1], X[3], offs, colv, valv, 2.0f, 1);

    k_gemm<<<(NROWS+127)/128, 256, 0, stream>>>(X[0], X[1], X[2], X[3], Wt, Y);

    dim3 gmean((MM+511)/512, BB);
    k_colmean<<<gmean, 128, 0, stream>>>(Y, sacc);
    k_se<<<BB, 128, 0, stream>>>(sacc, Wd, bd, Wu, bu, u);
    k_scale<<<25000, 256, 0, stream>>>(Y, u, out);
}

// Round 2
// 964.452 us; speedup vs baseline: 1.1543x; 1.1543x over previous
//
#include <hip/hip_runtime.h>
#include <hip/hip_bf16.h>

#define BB 4
#define MM 50000
#define FINF 128
#define FOUTF 128
#define KCH 4
#define EE 800000
#define NROWS (BB*MM)      // 200000
#define XC 512             // columns of X = B*FIN
#define CD 512             // reduction dim = FIN*K

__device__ __forceinline__ float bf2f(unsigned short u){
    union{unsigned int i; float f;} v; v.i = ((unsigned int)u) << 16; return v.f;
}
__device__ __forceinline__ unsigned short f2bf(float f){
    union{float f; unsigned int i;} v; v.f = f;
    unsigned int r = v.i + 0x7FFF + ((v.i >> 16) & 1);   // RNE
    return (unsigned short)(r >> 16);
}

typedef __bf16 bf16x8 __attribute__((ext_vector_type(8)));
typedef float  f32x4  __attribute__((ext_vector_type(4)));

// ---- X0[m][b*128+f] = bf16(x[b][m][f]) ----
__global__ __launch_bounds__(256) void k_init_x0(const float* __restrict__ x,
                                                 unsigned short* __restrict__ X0){
    int tid = blockIdx.x*256 + threadIdx.x;          // one float4 each
    if (tid >= BB*MM*FINF/4) return;
    int f4 = tid & 31;
    int t  = tid >> 5;                               // b*MM + m
    int m  = t % MM, b = t / MM;
    float4 v = ((const float4*)x)[tid];
    ushort4 o;
    o.x = f2bf(v.x); o.y = f2bf(v.y); o.z = f2bf(v.z); o.w = f2bf(v.w);
    *(ushort4*)(X0 + (size_t)m*XC + b*FINF + f4*4) = o;
}

// ---- Wt[n][k*128+f] = bf16(kernel[(f*K+k)*128 + n]) ----
__global__ __launch_bounds__(256) void k_prepw(const float* __restrict__ kern,
                                               unsigned short* __restrict__ Wt){
    int tid = blockIdx.x*256 + threadIdx.x;          // 65536
    int c = tid & 511, n = tid >> 9;
    int kc = c >> 7, f = c & 127;
    Wt[n*CD + c] = f2bf(kern[(f*KCH + kc)*FOUTF + n]);
}

// ---- CSR build ----
__global__ __launch_bounds__(256) void k_hist(const int* __restrict__ rows, int* __restrict__ counts){
    int e = blockIdx.x*256 + threadIdx.x;
    if (e < EE) atomicAdd(&counts[rows[e]], 1);
}

__global__ __launch_bounds__(1024) void k_scan(const int* __restrict__ counts,
                                               int* __restrict__ offs, int* __restrict__ cursor){
    __shared__ int part[1024];
    const int CH = (MM + 1023) / 1024;               // 49
    int t = threadIdx.x;
    int lo = t*CH; if (lo > MM) lo = MM;
    int hi = lo + CH; if (hi > MM) hi = MM;
    int s = 0;
    for (int i = lo; i < hi; ++i) s += counts[i];
    part[t] = s; __syncthreads();
    for (int d = 1; d < 1024; d <<= 1){
        int v = (t >= d) ? part[t-d] : 0;
        __syncthreads();
        part[t] += v;
        __syncthreads();
    }
    int run = (t == 0) ? 0 : part[t-1];
    for (int i = lo; i < hi; ++i){
        offs[i] = run; cursor[i] = run; run += counts[i];
    }
    if (t == 1023) offs[MM] = part[1023];
}

__global__ __launch_bounds__(256) void k_scatter(const int* __restrict__ rows, const int* __restrict__ cols,
                                                 const float* __restrict__ vals, int* __restrict__ cursor,
                                                 int* __restrict__ colv, float* __restrict__ valv){
    int e = blockIdx.x*256 + threadIdx.x;
    if (e >= EE) return;
    int r = rows[e];
    int pos = atomicAdd(&cursor[r], 1);
    colv[pos] = cols[e]; valv[pos] = vals[e];
}

// ---- Xout = alpha * (L @ Xin) - (sub ? Xprev : 0), one block per row ----
__global__ __launch_bounds__(128) void k_spmm(const unsigned short* __restrict__ Xin,
                                              const unsigned short* __restrict__ Xprev,
                                              unsigned short* __restrict__ Xout,
                                              const int* __restrict__ offs,
                                              const int* __restrict__ colv,
                                              const float* __restrict__ valv,
                                              float alpha, int sub){
    int m = blockIdx.x, t = threadIdx.x;
    int c0 = t*4;
    int start = offs[m], end = offs[m+1];
    float a0=0.f, a1=0.f, a2=0.f, a3=0.f;
    for (int j = start; j < end; ++j){
        int col = colv[j]; float val = valv[j];
        ushort4 xv = *(const ushort4*)(Xin + (size_t)col*XC + c0);
        a0 += val*bf2f(xv.x); a1 += val*bf2f(xv.y);
        a2 += val*bf2f(xv.z); a3 += val*bf2f(xv.w);
    }
    a0 *= alpha; a1 *= alpha; a2 *= alpha; a3 *= alpha;
    if (sub){
        ushort4 pv = *(const ushort4*)(Xprev + (size_t)m*XC + c0);
        a0 -= bf2f(pv.x); a1 -= bf2f(pv.y); a2 -= bf2f(pv.z); a3 -= bf2f(pv.w);
    }
    ushort4 o; o.x = f2bf(a0); o.y = f2bf(a1); o.z = f2bf(a2); o.w = f2bf(a3);
    *(ushort4*)(Xout + (size_t)m*XC + c0) = o;
}

// ---- Y[r][n] = relu(sum_c A[r][c]*Wt[n][c]); A[r][k*128+f] = Xk[m][b*128+f], r=b*M+m ----
__global__ __launch_bounds__(256) void k_gemm(const unsigned short* __restrict__ X0,
                                              const unsigned short* __restrict__ X1,
                                              const unsigned short* __restrict__ X2,
                                              const unsigned short* __restrict__ X3,
                                              const unsigned short* __restrict__ Wt,
                                              float* __restrict__ Y){
    const int wave = threadIdx.x >> 6;
    const int lane = threadIdx.x & 63;
    const int l16  = lane & 15;
    const int g    = lane >> 4;                       // 0..3
    const int r0   = blockIdx.x*128 + wave*32;
    int ra0 = r0 + l16;      if (ra0 >= NROWS) ra0 = NROWS-1;
    int ra1 = r0 + 16 + l16; if (ra1 >= NROWS) ra1 = NROWS-1;
    const size_t aoff0 = (size_t)(ra0 % MM)*XC + (ra0 / MM)*FINF + g*8;
    const size_t aoff1 = (size_t)(ra1 % MM)*XC + (ra1 / MM)*FINF + g*8;
    const int wrow = l16*CD + g*8;                    // base into Wt

    f32x4 acc[2][8];
    #pragma unroll
    for (int i = 0; i < 2; ++i)
        #pragma unroll
        for (int j = 0; j < 8; ++j) acc[i][j] = (f32x4){0.f,0.f,0.f,0.f};

    const unsigned short* const Xs[4] = {X0, X1, X2, X3};
    #pragma unroll
    for (int kb = 0; kb < 4; ++kb){
        const unsigned short* Xb = Xs[kb];
        #pragma unroll
        for (int ki = 0; ki < 4; ++ki){
            const int f0 = ki*32;
            bf16x8 a0 = *(const bf16x8*)(Xb + aoff0 + f0);
            bf16x8 a1 = *(const bf16x8*)(Xb + aoff1 + f0);
            const int c0 = (kb*4 + ki)*32;            // reduction offset (g*8 already in wrow)
            #pragma unroll
            for (int ns = 0; ns < 8; ++ns){
                bf16x8 bb = *(const bf16x8*)(Wt + wrow + ns*16*CD + c0);
                acc[0][ns] = __builtin_amdgcn_mfma_f32_16x16x32_bf16(a0, bb, acc[0][ns], 0, 0, 0);
                acc[1][ns] = __builtin_amdgcn_mfma_f32_16x16x32_bf16(a1, bb, acc[1][ns], 0, 0, 0);
            }
        }
    }
    #pragma unroll
    for (int msub = 0; msub < 2; ++msub){
        #pragma unroll
        for (int reg = 0; reg < 4; ++reg){
            int r = r0 + msub*16 + g*4 + reg;
            if (r < NROWS){
                #pragma unroll
                for (int ns = 0; ns < 8; ++ns){
                    float v = acc[msub][ns][reg];
                    Y[(size_t)r*FOUTF + ns*16 + l16] = v > 0.f ? v : 0.f;
                }
            }
        }
    }
}

// ---- column sums of Y per batch: grid (256 chunks, B), 256 thr ----
// wave layout: c4 = t&31 covers a full 512B row segment as float4;
// rs = t>>5 gives 8 rows in flight; adjacent rows -> adjacent 512B segs.
__global__ __launch_bounds__(256) void k_colmean(const float* __restrict__ Y, float* __restrict__ sacc){
    int b = blockIdx.y, t = threadIdx.x;
    int c4 = t & 31, rs = t >> 5;
    const int rows = (MM + gridDim.x - 1) / gridDim.x;
    int m0 = blockIdx.x * rows;
    int mend = m0 + rows; if (mend > MM) mend = MM;
    float4 s = {0.f,0.f,0.f,0.f};
    for (int m = m0 + rs; m < mend; m += 8){
        float4 v = *(const float4*)(Y + ((size_t)b*MM + m)*FOUTF + c4*4);
        s.x += v.x; s.y += v.y; s.z += v.z; s.w += v.w;
    }
    __shared__ float4 red[8][32];
    red[rs][c4] = s;
    __syncthreads();
    if (t < 32){
        float4 a = red[0][t];
        #pragma unroll
        for (int i = 1; i < 8; ++i){
            float4 v = red[i][t];
            a.x += v.x; a.y += v.y; a.z += v.z; a.w += v.w;
        }
        atomicAdd(&sacc[b*FOUTF + t*4 + 0], a.x);
        atomicAdd(&sacc[b*FOUTF + t*4 + 1], a.y);
        atomicAdd(&sacc[b*FOUTF + t*4 + 2], a.z);
        atomicAdd(&sacc[b*FOUTF + t*4 + 3], a.w);
    }
}

// ---- SE MLP: u = sigmoid(swish(mean @ Wd + bd) @ Wu + bu) ----
__global__ __launch_bounds__(128) void k_se(const float* __restrict__ sacc,
                                            const float* __restrict__ Wd, const float* __restrict__ bd,
                                            const float* __restrict__ Wu, const float* __restrict__ bu,
                                            float* __restrict__ u){
    int b = blockIdx.x, t = threadIdx.x;
    __shared__ float sm[128];
    __shared__ float dsh[16];
    sm[t] = sacc[b*FOUTF + t] * (1.0f/MM);
    __syncthreads();
    if (t < 16){
        float a = bd[t];
        for (int f = 0; f < 128; ++f) a += sm[f]*Wd[f*16 + t];
        dsh[t] = a / (1.f + expf(-a));                // swish
    }
    __syncthreads();
    float a = bu[t];
    for (int j = 0; j < 16; ++j) a += dsh[j]*Wu[j*FOUTF + t];
    u[b*FOUTF + t] = 1.f/(1.f + expf(-a));
}

// ---- out = Y * u[b] ----
__global__ __launch_bounds__(256) void k_scale(const float* __restrict__ Y, const float* __restrict__ u,
                                               float* __restrict__ out){
    int tid = blockIdx.x*256 + threadIdx.x;
    if (tid >= NROWS*FOUTF/4) return;
    int b  = tid / (MM*FOUTF/4);
    int f4 = tid & 31;
    float4 yv = ((const float4*)Y)[tid];
    float4 uv = *(const float4*)(u + b*FOUTF + f4*4);
    float4 o;
    o.x = yv.x*uv.x; o.y = yv.y*uv.y; o.z = yv.z*uv.z; o.w = yv.w*uv.w;
    ((float4*)out)[tid] = o;
}

extern "C" void kernel_launch(void* const* d_in, const int* in_sizes, int n_in,
                              void* d_out, int out_size, void* d_ws, size_t ws_size,
                              hipStream_t stream){
    (void)in_sizes; (void)n_in; (void)out_size; (void)ws_size;
    const float* x    = (const float*)d_in[0];
    const float* lv   = (const float*)d_in[1];
    const int*   lr   = (const int*)d_in[2];
    const int*   lc   = (const int*)d_in[3];
    const float* kern = (const float*)d_in[4];
    const float* Wd   = (const float*)d_in[5];
    const float* bd   = (const float*)d_in[6];
    const float* Wu   = (const float*)d_in[7];
    const float* bu   = (const float*)d_in[8];
    float* out = (float*)d_out;

    char* w = (char*)d_ws;
    size_t off = 0;
    auto take = [&](size_t bytes)->char*{
        char* p = w + off; off += (bytes + 255) & ~(size_t)255; return p;
    };
    unsigned short* X[4];
    for (int i = 0; i < 4; ++i) X[i] = (unsigned short*)take((size_t)MM*XC*2);
    float* Y           = (float*)take((size_t)NROWS*FOUTF*4);
    unsigned short* Wt = (unsigned short*)take((size_t)FOUTF*CD*2);
    int* counts        = (int*)take((size_t)MM*4);
    int* offs          = (int*)take((size_t)(MM+1)*4);
    int* cursor        = (int*)take((size_t)MM*4);
    int* colv          = (int*)take((size_t)EE*4);
    float* valv        = (float*)take((size_t)EE*4);
    float* sacc        = (float*)take((size_t)BB*FOUTF*4);
    float* u           = (float*)take((size_t)BB*FOUTF*4);

    hipMemsetAsync(counts, 0, MM*4, stream);
    hipMemsetAsync(sacc, 0, BB*FOUTF*4, stream);

    k_init_x0<<<25000, 256, 0, stream>>>(x, X[0]);
    k_prepw<<<256, 256, 0, stream>>>(kern, Wt);
    k_hist<<<(EE+255)/256, 256, 0, stream>>>(lr, counts);
    k_scan<<<1, 1024, 0, stream>>>(counts, offs, cursor);
    k_scatter<<<(EE+255)/256, 256, 0, stream>>>(lr, lc, lv, cursor, colv, valv);

    k_spmm<<<MM, 128, 0, stream>>>(X[0], X[0], X[1], offs, colv, valv, 1.0f, 0);
    k_spmm<<<MM, 128, 0, stream>>>(X[1], X[0], X[2], offs, colv, valv, 2.0f, 1);
    k_spmm<<<MM, 128, 0, stream>>>(X[2], X[1], X[3], offs, colv, valv, 2.0f, 1);

    k_gemm<<<(NROWS+127)/128, 256, 0, stream>>>(X[0], X[1], X[2], X[3], Wt, Y);

    dim3 gmean(256, BB);
    k_colmean<<<gmean, 256, 0, stream>>>(Y, sacc);
    k_se<<<BB, 128, 0, stream>>>(sacc, Wd, bd, Wu, bu, u);
    k_scale<<<25000, 256, 0, stream>>>(Y, u, out);
}

// Round 3
// 914.780 us; speedup vs baseline: 1.2169x; 1.0543x over previous
//
#include <hip/hip_runtime.h>
#include <hip/hip_bf16.h>

#define BB 4
#define MM 50000
#define FINF 128
#define FOUTF 128
#define KCH 4
#define EE 800000
#define NROWS (BB*MM)      // 200000
#define XC 512             // columns of X = B*FIN
#define CD 512             // reduction dim = FIN*K

__device__ __forceinline__ float bf2f(unsigned short u){
    union{unsigned int i; float f;} v; v.i = ((unsigned int)u) << 16; return v.f;
}
__device__ __forceinline__ unsigned short f2bf(float f){
    union{float f; unsigned int i;} v; v.f = f;
    unsigned int r = v.i + 0x7FFF + ((v.i >> 16) & 1);   // RNE
    return (unsigned short)(r >> 16);
}

typedef __bf16 bf16x8 __attribute__((ext_vector_type(8)));
typedef float  f32x4  __attribute__((ext_vector_type(4)));

// ---- X0[m][b*128+f] = bf16(x[b][m][f]) ----
__global__ __launch_bounds__(256) void k_init_x0(const float* __restrict__ x,
                                                 unsigned short* __restrict__ X0){
    int tid = blockIdx.x*256 + threadIdx.x;          // one float4 each
    if (tid >= BB*MM*FINF/4) return;
    int f4 = tid & 31;
    int t  = tid >> 5;                               // b*MM + m
    int m  = t % MM, b = t / MM;
    float4 v = ((const float4*)x)[tid];
    ushort4 o;
    o.x = f2bf(v.x); o.y = f2bf(v.y); o.z = f2bf(v.z); o.w = f2bf(v.w);
    *(ushort4*)(X0 + (size_t)m*XC + b*FINF + f4*4) = o;
}

// ---- Wt swizzled into MFMA B-fragment order ----
// gemm wants: lane (g=lane>>4, l16=lane&15), frag (ns, ks), elem j ->
//   B[n = ns*16+l16][c = ks*32+g*8+j], stored at ((ns*16+ks)*64 + lane)*8 + j
// value meaning: c = kc*128 + f  ->  kernel[(f*K+kc)*FOUT + n]
__global__ __launch_bounds__(256) void k_prepw(const float* __restrict__ kern,
                                               unsigned short* __restrict__ Wt){
    int tid = blockIdx.x*256 + threadIdx.x;          // 65536
    int c = tid & 511, n = tid >> 9;
    int kc = c >> 7, f = c & 127;
    int ns = n >> 4, l16 = n & 15;
    int ks = c >> 5, rem = c & 31, g = rem >> 3, j = rem & 7;
    int lane = g*16 + l16;
    Wt[((ns*16 + ks)*64 + lane)*8 + j] = f2bf(kern[(f*KCH + kc)*FOUTF + n]);
}

// ---- CSR build ----
__global__ __launch_bounds__(256) void k_hist(const int* __restrict__ rows, int* __restrict__ counts){
    int e = blockIdx.x*256 + threadIdx.x;
    if (e < EE) atomicAdd(&counts[rows[e]], 1);
}

__global__ __launch_bounds__(1024) void k_scan(const int* __restrict__ counts,
                                               int* __restrict__ offs, int* __restrict__ cursor){
    __shared__ int part[1024];
    const int CH = (MM + 1023) / 1024;               // 49
    int t = threadIdx.x;
    int lo = t*CH; if (lo > MM) lo = MM;
    int hi = lo + CH; if (hi > MM) hi = MM;
    int s = 0;
    for (int i = lo; i < hi; ++i) s += counts[i];
    part[t] = s; __syncthreads();
    for (int d = 1; d < 1024; d <<= 1){
        int v = (t >= d) ? part[t-d] : 0;
        __syncthreads();
        part[t] += v;
        __syncthreads();
    }
    int run = (t == 0) ? 0 : part[t-1];
    for (int i = lo; i < hi; ++i){
        offs[i] = run; cursor[i] = run; run += counts[i];
    }
    if (t == 1023) offs[MM] = part[1023];
}

__global__ __launch_bounds__(256) void k_scatter(const int* __restrict__ rows, const int* __restrict__ cols,
                                                 const float* __restrict__ vals, int* __restrict__ cursor,
                                                 int* __restrict__ colv, float* __restrict__ valv){
    int e = blockIdx.x*256 + threadIdx.x;
    if (e >= EE) return;
    int r = rows[e];
    int pos = atomicAdd(&cursor[r], 1);
    colv[pos] = cols[e]; valv[pos] = vals[e];
}

// ---- Xout = alpha * (L @ Xin) - (sub ? Xprev : 0), one block per row ----
__global__ __launch_bounds__(128) void k_spmm(const unsigned short* __restrict__ Xin,
                                              const unsigned short* __restrict__ Xprev,
                                              unsigned short* __restrict__ Xout,
                                              const int* __restrict__ offs,
                                              const int* __restrict__ colv,
                                              const float* __restrict__ valv,
                                              float alpha, int sub){
    int m = blockIdx.x, t = threadIdx.x;
    int c0 = t*4;
    int start = offs[m], end = offs[m+1];
    float a0=0.f, a1=0.f, a2=0.f, a3=0.f;
    for (int j = start; j < end; ++j){
        int col = colv[j]; float val = valv[j];
        ushort4 xv = *(const ushort4*)(Xin + (size_t)col*XC + c0);
        a0 += val*bf2f(xv.x); a1 += val*bf2f(xv.y);
        a2 += val*bf2f(xv.z); a3 += val*bf2f(xv.w);
    }
    a0 *= alpha; a1 *= alpha; a2 *= alpha; a3 *= alpha;
    if (sub){
        ushort4 pv = *(const ushort4*)(Xprev + (size_t)m*XC + c0);
        a0 -= bf2f(pv.x); a1 -= bf2f(pv.y); a2 -= bf2f(pv.z); a3 -= bf2f(pv.w);
    }
    ushort4 o; o.x = f2bf(a0); o.y = f2bf(a1); o.z = f2bf(a2); o.w = f2bf(a3);
    *(ushort4*)(Xout + (size_t)m*XC + c0) = o;
}

// ---- GEMM: wave tile 64 rows x 128 cols, B fragments coalesced, 2-stage pipeline ----
__global__ __launch_bounds__(256, 2) void k_gemm(const unsigned short* __restrict__ X0,
                                                 const unsigned short* __restrict__ X1,
                                                 const unsigned short* __restrict__ X2,
                                                 const unsigned short* __restrict__ X3,
                                                 const unsigned short* __restrict__ Wt,
                                                 float* __restrict__ Y){
    const int wave = threadIdx.x >> 6;
    const int lane = threadIdx.x & 63;
    const int l16  = lane & 15;
    const int g    = lane >> 4;                       // 0..3
    const int r0   = blockIdx.x*256 + wave*64;

    int aoff[4];                                      // short-index offsets into X
    #pragma unroll
    for (int i = 0; i < 4; ++i){
        int ra = r0 + i*16 + l16;
        if (ra >= NROWS) ra = NROWS-1;
        aoff[i] = (ra % MM)*XC + (ra / MM)*FINF + g*8;
    }

    const unsigned short* const Xs[4] = {X0, X1, X2, X3};

    f32x4 acc[4][8];
    #pragma unroll
    for (int i = 0; i < 4; ++i)
        #pragma unroll
        for (int j = 0; j < 8; ++j) acc[i][j] = (f32x4){0.f,0.f,0.f,0.f};

    bf16x8 a_cur[4], b_cur[8], a_nxt[4], b_nxt[8];

    {   // preload ks = 0
        const unsigned short* Xb = Xs[0];
        #pragma unroll
        for (int i = 0; i < 4; ++i) a_cur[i] = *(const bf16x8*)(Xb + aoff[i]);
        #pragma unroll
        for (int ns = 0; ns < 8; ++ns) b_cur[ns] = *(const bf16x8*)(Wt + (ns*16)*512 + lane*8);
    }

    #pragma unroll
    for (int ks = 0; ks < 16; ++ks){
        if (ks < 15){
            const int kn = ks + 1;
            const unsigned short* Xb = Xs[kn >> 2];
            const int f0 = (kn & 3)*32;
            #pragma unroll
            for (int i = 0; i < 4; ++i) a_nxt[i] = *(const bf16x8*)(Xb + aoff[i] + f0);
            #pragma unroll
            for (int ns = 0; ns < 8; ++ns) b_nxt[ns] = *(const bf16x8*)(Wt + (ns*16 + kn)*512 + lane*8);
        }
        #pragma unroll
        for (int ns = 0; ns < 8; ++ns)
            #pragma unroll
            for (int i = 0; i < 4; ++i)
                acc[i][ns] = __builtin_amdgcn_mfma_f32_16x16x32_bf16(a_cur[i], b_cur[ns], acc[i][ns], 0, 0, 0);
        #pragma unroll
        for (int i = 0; i < 4; ++i) a_cur[i] = a_nxt[i];
        #pragma unroll
        for (int ns = 0; ns < 8; ++ns) b_cur[ns] = b_nxt[ns];
    }

    #pragma unroll
    for (int i = 0; i < 4; ++i){
        #pragma unroll
        for (int reg = 0; reg < 4; ++reg){
            int r = r0 + i*16 + g*4 + reg;
            if (r < NROWS){
                #pragma unroll
                for (int ns = 0; ns < 8; ++ns){
                    float v = acc[i][ns][reg];
                    Y[(size_t)r*FOUTF + ns*16 + l16] = v > 0.f ? v : 0.f;
                }
            }
        }
    }
}

// ---- column sums of Y per batch: grid (256 chunks, B), 256 thr ----
__global__ __launch_bounds__(256) void k_colmean(const float* __restrict__ Y, float* __restrict__ sacc){
    int b = blockIdx.y, t = threadIdx.x;
    int c4 = t & 31, rs = t >> 5;
    const int rows = (MM + gridDim.x - 1) / gridDim.x;
    int m0 = blockIdx.x * rows;
    int mend = m0 + rows; if (mend > MM) mend = MM;
    float4 s = {0.f,0.f,0.f,0.f};
    for (int m = m0 + rs; m < mend; m += 8){
        float4 v = *(const float4*)(Y + ((size_t)b*MM + m)*FOUTF + c4*4);
        s.x += v.x; s.y += v.y; s.z += v.z; s.w += v.w;
    }
    __shared__ float4 red[8][32];
    red[rs][c4] = s;
    __syncthreads();
    if (t < 32){
        float4 a = red[0][t];
        #pragma unroll
        for (int i = 1; i < 8; ++i){
            float4 v = red[i][t];
            a.x += v.x; a.y += v.y; a.z += v.z; a.w += v.w;
        }
        atomicAdd(&sacc[b*FOUTF + t*4 + 0], a.x);
        atomicAdd(&sacc[b*FOUTF + t*4 + 1], a.y);
        atomicAdd(&sacc[b*FOUTF + t*4 + 2], a.z);
        atomicAdd(&sacc[b*FOUTF + t*4 + 3], a.w);
    }
}

// ---- SE MLP: u = sigmoid(swish(mean @ Wd + bd) @ Wu + bu) ----
__global__ __launch_bounds__(128) void k_se(const float* __restrict__ sacc,
                                            const float* __restrict__ Wd, const float* __restrict__ bd,
                                            const float* __restrict__ Wu, const float* __restrict__ bu,
                                            float* __restrict__ u){
    int b = blockIdx.x, t = threadIdx.x;
    __shared__ float sm[128];
    __shared__ float dsh[16];
    sm[t] = sacc[b*FOUTF + t] * (1.0f/MM);
    __syncthreads();
    if (t < 16){
        float a = bd[t];
        for (int f = 0; f < 128; ++f) a += sm[f]*Wd[f*16 + t];
        dsh[t] = a / (1.f + expf(-a));                // swish
    }
    __syncthreads();
    float a = bu[t];
    for (int j = 0; j < 16; ++j) a += dsh[j]*Wu[j*FOUTF + t];
    u[b*FOUTF + t] = 1.f/(1.f + expf(-a));
}

// ---- out = Y * u[b] ----
__global__ __launch_bounds__(256) void k_scale(const float* __restrict__ Y, const float* __restrict__ u,
                                               float* __restrict__ out){
    int tid = blockIdx.x*256 + threadIdx.x;
    if (tid >= NROWS*FOUTF/4) return;
    int b  = tid / (MM*FOUTF/4);
    int f4 = tid & 31;
    float4 yv = ((const float4*)Y)[tid];
    float4 uv = *(const float4*)(u + b*FOUTF + f4*4);
    float4 o;
    o.x = yv.x*uv.x; o.y = yv.y*uv.y; o.z = yv.z*uv.z; o.w = yv.w*uv.w;
    ((float4*)out)[tid] = o;
}

extern "C" void kernel_launch(void* const* d_in, const int* in_sizes, int n_in,
                              void* d_out, int out_size, void* d_ws, size_t ws_size,
                              hipStream_t stream){
    (void)in_sizes; (void)n_in; (void)out_size; (void)ws_size;
    const float* x    = (const float*)d_in[0];
    const float* lv   = (const float*)d_in[1];
    const int*   lr   = (const int*)d_in[2];
    const int*   lc   = (const int*)d_in[3];
    const float* kern = (const float*)d_in[4];
    const float* Wd   = (const float*)d_in[5];
    const float* bd   = (const float*)d_in[6];
    const float* Wu   = (const float*)d_in[7];
    const float* bu   = (const float*)d_in[8];
    float* out = (float*)d_out;

    char* w = (char*)d_ws;
    size_t off = 0;
    auto take = [&](size_t bytes)->char*{
        char* p = w + off; off += (bytes + 255) & ~(size_t)255; return p;
    };
    unsigned short* X[4];
    for (int i = 0; i < 4; ++i) X[i] = (unsigned short*)take((size_t)MM*XC*2);
    float* Y           = (float*)take((size_t)NROWS*FOUTF*4);
    unsigned short* Wt = (unsigned short*)take((size_t)FOUTF*CD*2);
    int* counts        = (int*)take((size_t)MM*4);
    int* offs          = (int*)take((size_t)(MM+1)*4);
    int* cursor        = (int*)take((size_t)MM*4);
    int* colv          = (int*)take((size_t)EE*4);
    float* valv        = (float*)take((size_t)EE*4);
    float* sacc        = (float*)take((size_t)BB*FOUTF*4);
    float* u           = (float*)take((size_t)BB*FOUTF*4);

    hipMemsetAsync(counts, 0, MM*4, stream);
    hipMemsetAsync(sacc, 0, BB*FOUTF*4, stream);

    k_init_x0<<<25000, 256, 0, stream>>>(x, X[0]);
    k_prepw<<<256, 256, 0, stream>>>(kern, Wt);
    k_hist<<<(EE+255)/256, 256, 0, stream>>>(lr, counts);
    k_scan<<<1, 1024, 0, stream>>>(counts, offs, cursor);
    k_scatter<<<(EE+255)/256, 256, 0, stream>>>(lr, lc, lv, cursor, colv, valv);

    k_spmm<<<MM, 128, 0, stream>>>(X[0], X[0], X[1], offs, colv, valv, 1.0f, 0);
    k_spmm<<<MM, 128, 0, stream>>>(X[1], X[0], X[2], offs, colv, valv, 2.0f, 1);
    k_spmm<<<MM, 128, 0, stream>>>(X[2], X[1], X[3], offs, colv, valv, 2.0f, 1);

    k_gemm<<<(NROWS+255)/256, 256, 0, stream>>>(X[0], X[1], X[2], X[3], Wt, Y);

    dim3 gmean(256, BB);
    k_colmean<<<gmean, 256, 0, stream>>>(Y, sacc);
    k_se<<<BB, 128, 0, stream>>>(sacc, Wd, bd, Wu, bu, u);
    k_scale<<<25000, 256, 0, stream>>>(Y, u, out);
}